// Round 1
// baseline (1159.959 us; speedup 1.0000x reference)
//
#include <hip/hip_runtime.h>

// Problem: B=2, S=2304, C=1280, NH=8, DH=160, MH=64, SR=48, BH=16
// R7: 957us, attn 2x360us latency-bound (MfmaUtil 6%, VALU 12%, HBM 4%).
// R8: barrier-free attn. K read direct from global (like V) -> no LDS staging,
// no __syncthreads in the loop, waves free-run. Softmax reductions via DPP
// (VALU-latency) instead of shfl_xor (DS-pipe). Mask prefetched one iter ahead.
// 1/sqrt(DH) folded into Q at gemm epilogue. K stored unpadded; convK removed.

typedef unsigned short u16;
typedef unsigned int   u32;
typedef unsigned char  u8;
typedef __attribute__((ext_vector_type(8))) short bf16x8;   // 8 bf16 = 4 VGPRs
typedef __attribute__((ext_vector_type(4))) float f32x4;

#define MFMA16(a,b,c) __builtin_amdgcn_mfma_f32_16x16x32_bf16((a),(b),(c),0,0,0)
#define INVS 0.07905694150420949f                 // 1/sqrt(160)

__device__ __forceinline__ u16 f2b(float f) {            // fp32 -> bf16 RNE
  u32 u = __float_as_uint(f);
  return (u16)((u + 0x7fffu + ((u >> 16) & 1u)) >> 16);
}
__device__ __forceinline__ float b2f(u16 v) { return __uint_as_float(((u32)v) << 16); }

// DPP reduction over a 16-lane row (exactly our l16 domain):
// quad_perm(1,0,3,2)=0xB1, quad_perm(2,3,0,1)=0x4E, row_half_mirror=0x141, row_mirror=0x140
#define DPPF(x, ctrl) __int_as_float(__builtin_amdgcn_update_dpp(0, __float_as_int(x), (ctrl), 0xf, 0xf, true))
__device__ __forceinline__ float row_max16(float x) {
  x = fmaxf(x, DPPF(x, 0xB1));
  x = fmaxf(x, DPPF(x, 0x4E));
  x = fmaxf(x, DPPF(x, 0x141));
  x = fmaxf(x, DPPF(x, 0x140));
  return x;
}
__device__ __forceinline__ float row_sum16(float x) {
  x += DPPF(x, 0xB1);
  x += DPPF(x, 0x4E);
  x += DPPF(x, 0x141);
  x += DPPF(x, 0x140);
  return x;
}

// ---------------- mask-mode detector: 0=i32, 1=u8, 2=bf16, 3=f32 ----------------
__global__ __launch_bounds__(256) void maskdet(const u32* __restrict__ mid, u32* mode)
{
  __shared__ int a0, a1, a2, a3;
  int tid = threadIdx.x;
  if (tid == 0) { a0 = 1; a1 = 1; a2 = 1; a3 = 0; }
  __syncthreads();
  #pragma unroll
  for (int j = 0; j < 4; j++) {
    u32 w = mid[tid*4 + j];                      // first 4 KiB, in-bounds for all dtypes
    if (w > 1u)                      atomicAnd(&a0, 0);  // not i32 bools
    if (w & 0xFEFEFEFEu)             atomicAnd(&a1, 0);  // not u8 bools
    if (w != 0u && w != 0x3F800000u) atomicAnd(&a2, 0);  // not f32 {0,1}
    if ((w & 0xFFFFu) == 0x3F80u)    atomicOr(&a3, 1);   // bf16 1.0 in low half
  }
  __syncthreads();
  if (tid == 0) mode[0] = a0 ? 0u : (a1 ? 1u : (a3 ? 2u : (a2 ? 3u : 0u)));
}

// ---------------- nearest-downsample masks 64x64 -> 48x48 flattened to S ----------------
__global__ void maskprep(const void* mid, const float* __restrict__ mig_in,
                         float* __restrict__ mk, float* __restrict__ mg, const u32* mode)
{
  int j = blockIdx.x*256 + threadIdx.x;
  if (j >= 2*2304) return;
  u32 md = mode[0];
  int b = j / 2304, s = j % 2304;
  int i = s / 48, jj = s % 48;
  int ih = (i*4)/3, iw = (jj*4)/3;        // arange(48)*64//48
  int src = b*4096 + ih*64 + iw;
  bool on;
  if      (md == 0) on = ((const int*)mid)[src] != 0;
  else if (md == 1) on = ((const u8*)mid)[src]  != 0;
  else if (md == 2) on = ((const u16*)mid)[src] != 0;
  else              on = ((const float*)mid)[src] != 0.0f;
  mk[j] = on ? 1.0f : 0.0f;
  mg[j] = mig_in[src];                     // mask_ig is fp32
}

// ---------------- transpose weights: fp32 W[k][n] -> bf16 WT[n][k], 4 matrices --------------
__global__ __launch_bounds__(256) void transpose_w(
    const float* __restrict__ W0, const float* __restrict__ W1,
    const float* __restrict__ W2, const float* __restrict__ W3, u16* __restrict__ WT)
{
  __shared__ u16 t[32][33];
  int z = blockIdx.z;
  const float* s = (z==0)?W0:(z==1)?W1:(z==2)?W2:W3;
  u16* d = WT + (size_t)z*1280*1280;
  int tx = threadIdx.x & 31, ty = (threadIdx.x >> 5) * 4;
  int x = blockIdx.x*32 + tx;          // src col (n)
  int y = blockIdx.y*32 + ty;          // src row (k)
  #pragma unroll
  for (int i=0;i<4;i++) t[ty+i][tx] = f2b(s[(size_t)(y+i)*1280 + x]);
  __syncthreads();
  int x2 = blockIdx.y*32 + tx, y2 = blockIdx.x*32 + ty;
  #pragma unroll
  for (int i=0;i<4;i++) d[(size_t)(y2+i)*1280 + x2] = t[tx][ty+i];   // WT[n][k] = W[k][n]
}

// ---------------- convert fp32 -> bf16 (unpadded) ----------------
__global__ __launch_bounds__(256) void conv(const float* __restrict__ src, u16* __restrict__ dst, int n)
{
  for (int i = blockIdx.x*256 + threadIdx.x; i < n; i += gridDim.x*256)
    dst[i] = f2b(src[i]);
}

// ---------------- transpose store_vs fp32 [16][2304][160] -> bf16 vst[16][160][2304] ---------
__global__ __launch_bounds__(256) void transpose_vs(const float* __restrict__ src, u16* __restrict__ dst)
{
  __shared__ u16 t[32][33];
  int z = blockIdx.z;
  u16* d = dst + (size_t)z*160*2304;
  int tx = threadIdx.x & 31, ty = (threadIdx.x >> 5) * 4;
  int r0 = blockIdx.x*32, c0 = blockIdx.y*32;
  #pragma unroll
  for (int i=0;i<4;i++)
    t[ty+i][tx] = f2b(src[((size_t)z*2304 + r0+ty+i)*160 + c0+tx]);
  __syncthreads();
  #pragma unroll
  for (int i=0;i<4;i++) d[(size_t)(c0+ty+i)*2304 + r0+tx] = t[tx][ty+i]; // d[c][r] = s[r][c]
}

// ---------------- GEMM: 128x128 tile, BK=32, 4 waves (2x2), 16x16x32 MFMA ----------------
// kind 0: A=hidB, BT=WT[z]; z=0->q*INVS [bh][s][160], z=1->k [bh][s][160], z=2->v^T [bh][d][s]
// kind 1: A=comb, BT=WoT;   out = A@Wo + bias -> fp32 d_out
__global__ __launch_bounds__(256, 2) void gemm128(
    const u16* __restrict__ A, const u16* __restrict__ BT,
    u16* __restrict__ dq, u16* __restrict__ dk, u16* __restrict__ dvt,
    float* __restrict__ dout, const float* __restrict__ bias, int kind)
{
  __shared__ __align__(16) u16 As[128*40];   // pad 32->40: 80B stride breaks conflicts
  __shared__ __align__(16) u16 Bs[128*40];
  int tid = threadIdx.x;
  int m0 = blockIdx.x*128, n0 = blockIdx.y*128;
  int z = blockIdx.z;
  const u16* Bt = BT + (size_t)z*1280*1280;
  int w = tid>>6, lane = tid&63, quad = lane>>4, l16 = lane&15;
  int wm = w&1, wn = w>>1;
  int arow = tid>>1, acg = (tid&1)*16;
  f32x4 zero = {0.f,0.f,0.f,0.f};
  f32x4 acc[4][4];
  #pragma unroll
  for (int a=0;a<4;a++) { acc[a][0]=zero; acc[a][1]=zero; acc[a][2]=zero; acc[a][3]=zero; }
  const u16* ga = A  + (size_t)(m0+arow)*1280 + acg;
  const u16* gb = Bt + (size_t)(n0+arow)*1280 + acg;
  for (int k0 = 0; k0 < 1280; k0 += 32) {
    uint4 a0 = *(const uint4*)(ga + k0);
    uint4 a1 = *(const uint4*)(ga + k0 + 8);
    uint4 b0 = *(const uint4*)(gb + k0);
    uint4 b1 = *(const uint4*)(gb + k0 + 8);
    __syncthreads();
    *(uint4*)&As[arow*40 + acg]     = a0;
    *(uint4*)&As[arow*40 + acg + 8] = a1;
    *(uint4*)&Bs[arow*40 + acg]     = b0;
    *(uint4*)&Bs[arow*40 + acg + 8] = b1;
    __syncthreads();
    bf16x8 af[4], bfr[4];
    #pragma unroll
    for (int mt=0; mt<4; mt++) af[mt]  = *(const bf16x8*)&As[(wm*64+mt*16+l16)*40 + quad*8];
    #pragma unroll
    for (int nt=0; nt<4; nt++) bfr[nt] = *(const bf16x8*)&Bs[(wn*64+nt*16+l16)*40 + quad*8];
    #pragma unroll
    for (int mt=0; mt<4; mt++)
      #pragma unroll
      for (int nt=0; nt<4; nt++)
        acc[mt][nt] = MFMA16(af[mt], bfr[nt], acc[mt][nt]);
  }
  #pragma unroll
  for (int mt=0; mt<4; mt++) {
    int r0g = m0 + wm*64 + mt*16 + quad*4;          // 4 consecutive rows (reg 0..3)
    #pragma unroll
    for (int nt=0; nt<4; nt++) {
      int col = n0 + wn*64 + nt*16 + l16;
      if (kind == 1) {
        float bi = bias[col];
        #pragma unroll
        for (int r=0;r<4;r++) dout[(size_t)(r0g+r)*1280 + col] = acc[mt][nt][r] + bi;
      } else {
        int h = col/160, d = col%160;
        if (z == 2) {                               // v -> [bh][d][s], s consecutive
          int b = r0g/2304, s0 = r0g%2304;
          size_t base = ((size_t)((b*8+h)*160 + d))*2304 + s0;
          ushort4 pk;
          pk.x = f2b(acc[mt][nt][0]); pk.y = f2b(acc[mt][nt][1]);
          pk.z = f2b(acc[mt][nt][2]); pk.w = f2b(acc[mt][nt][3]);
          *(ushort4*)&dvt[base] = pk;
        } else {
          #pragma unroll
          for (int r=0;r<4;r++) {
            int rg = r0g + r;
            int b = rg/2304, s = rg%2304;
            if (z == 0) dq[((size_t)(b*8+h)*2304 + s)*160 + d] = f2b(acc[mt][nt][r] * INVS);
            else        dk[((size_t)(b*8+h)*2304 + s)*160 + d] = f2b(acc[mt][nt][r]);
          }
        }
      }
    }
  }
}

// ---------------- Attention (flash-style, online softmax), BARRIER-FREE. ----------------
// ip=0: self -> hs (bf16). ip=1: keys=sksB, V=vst, per-key mask, combine -> comb bf16.
// K and V B-frags read straight from global: 16 rows x 64B per instr, coalesced; 4 waves
// + 36 q-blocks of same bh share lines via L1/L2 (K slice 720KB/bh, L2-resident).
// No __syncthreads anywhere: waves free-run, latencies overlap. Softmax row-reduce via
// DPP (quad_perm/row_mirror over the 16-lane row) instead of DS-pipe shfl chains.
// Q pre-scaled by 1/sqrt(160) at gemm epilogue. Mask prefetched one iteration ahead.
__global__ __launch_bounds__(256, 4) void attn(
    const u16* __restrict__ qg,   // [16][2304][160], pre-scaled by INVS
    const u16* __restrict__ kg,   // [16][2304][160]
    const u16* __restrict__ vtg,  // [16][160][2304]
    const float* __restrict__ maskkey, const float* __restrict__ mig,
    u16* __restrict__ hs, u16* __restrict__ comb,
    const void* scaleptr, int ip)
{
  __shared__ __align__(16) u16 Ps[4*16*72];   // per-wave P relayout buffer (same-wave dep only)
  int bh = blockIdx.y, qt = blockIdx.x;
  int tid = threadIdx.x, w = tid>>6, lane = tid&63, quad = lane>>4, l16 = lane&15;
  int q0 = qt*64 + w*16;                       // wave's 16 queries

  bf16x8 aq[5];                                // Q frags: A[m=l16][k=quad*8+j], 5 ksteps
  {
    const u16* qrow = qg + ((size_t)bh*2304 + q0 + l16)*160 + quad*8;
    #pragma unroll
    for (int ks=0; ks<5; ks++) aq[ks] = *(const bf16x8*)(qrow + ks*32);
  }
  f32x4 zero = {0.f,0.f,0.f,0.f};
  f32x4 o[10];
  #pragma unroll
  for (int i=0;i<10;i++) o[i] = zero;
  float mrun[4] = {-1e30f,-1e30f,-1e30f,-1e30f};
  float lrun[4] = {0.f,0.f,0.f,0.f};

  const u16* vbase = vtg + ((size_t)bh*160 + l16)*2304 + quad*8;   // + nt*16 rows + key offs
  const u16* kbase = kg  + ((size_t)bh*2304 + l16)*160 + quad*8;   // + (kc*64+nt*16) rows

  float mcur[4] = {1.f,1.f,1.f,1.f};
  if (ip) {
    #pragma unroll
    for (int nt=0;nt<4;nt++) mcur[nt] = maskkey[(bh & 1)*2304 + nt*16 + l16];
  }

  for (int kc = 0; kc < 36; kc++) {
    // ---- prefetch next iteration's mask values (off the score critical path) ----
    float mnxt[4] = {1.f,1.f,1.f,1.f};
    if (ip && kc < 35) {
      #pragma unroll
      for (int nt=0;nt<4;nt++) mnxt[nt] = maskkey[(bh & 1)*2304 + (kc+1)*64 + nt*16 + l16];
    }

    // ---- scores S[16 q][64 keys] = Q K^T (Q pre-scaled), K direct from global ----
    f32x4 sc[4];
    bool keep[4];
    #pragma unroll
    for (int nt=0; nt<4; nt++) {
      const u16* kr = kbase + (size_t)(kc*64 + nt*16)*160;
      f32x4 s = zero;
      #pragma unroll
      for (int ks=0; ks<5; ks++) {
        bf16x8 bk = *(const bf16x8*)(kr + ks*32);
        s = MFMA16(aq[ks], bk, s);
      }
      keep[nt] = true;
      if (ip && mcur[nt] == 0.0f) {
        keep[nt] = false;
        #pragma unroll
        for (int r=0;r<4;r++) s[r] = -1e30f;
      }
      sc[nt] = s;
    }

    // ---- online softmax per query row (row = quad*4+r), DPP row reductions ----
    float p[4][4];
    #pragma unroll
    for (int r=0;r<4;r++) {
      float mrow = fmaxf(fmaxf(sc[0][r], sc[1][r]), fmaxf(sc[2][r], sc[3][r]));
      mrow = row_max16(mrow);
      float nm = fmaxf(mrun[r], mrow);
      float alpha = __expf(fminf(mrun[r] - nm, 0.f));
      mrun[r] = nm;
      float rs = 0.f;
      #pragma unroll
      for (int nt=0;nt<4;nt++) {
        float e = keep[nt] ? __expf(sc[nt][r] - nm) : 0.f;
        p[nt][r] = e; rs += e;
      }
      rs = row_sum16(rs);
      lrun[r] = lrun[r]*alpha + rs;
      #pragma unroll
      for (int nt2=0; nt2<10; nt2++) o[nt2][r] *= alpha;
    }

    // ---- P: C-layout -> A-layout via per-wave LDS (same-wave dep, DS pipe in-order) ----
    #pragma unroll
    for (int nt=0;nt<4;nt++)
      #pragma unroll
      for (int r=0;r<4;r++)
        Ps[(w*16 + quad*4 + r)*72 + nt*16 + l16] = f2b(p[nt][r]);

    // ---- O += P V, V B-frags straight from global (16B/lane, L1/L2-resident tile) ----
    #pragma unroll
    for (int kb=0; kb<2; kb++) {
      bf16x8 ap = *(const bf16x8*)&Ps[(w*16 + l16)*72 + kb*32 + quad*8];
      #pragma unroll
      for (int nt=0; nt<10; nt++) {
        bf16x8 bv = *(const bf16x8*)(vbase + (size_t)nt*16*2304 + kc*64 + kb*32);
        o[nt] = MFMA16(ap, bv, o[nt]);
      }
    }

    if (ip) {
      #pragma unroll
      for (int nt=0;nt<4;nt++) mcur[nt] = mnxt[nt];
    }
  }

  // ---- epilogue ----
  int b = bh>>3, h = bh&7;
  float scl = 0.f;
  if (ip) {                                   // scalar dtype self-detect (0.5 decodes both ways)
    u16 v0 = ((const u16*)scaleptr)[0];
    int e = (v0 >> 7) & 0xFF;
    scl = (v0 != 0 && e >= 100 && e <= 133) ? b2f(v0) : ((const float*)scaleptr)[0];
  }
  #pragma unroll
  for (int r=0;r<4;r++) {
    int s = q0 + quad*4 + r;
    float linv = (lrun[r] > 0.f) ? 1.0f/lrun[r] : 0.f;
    size_t base = ((size_t)b*2304 + s)*1280 + h*160;
    if (!ip) {
      #pragma unroll
      for (int nt=0;nt<10;nt++) hs[base + nt*16 + l16] = f2b(o[nt][r]*linv);
    } else {
      float f = mig[b*2304 + s]*scl*linv;    // mig uses TRUE b
      #pragma unroll
      for (int nt=0;nt<10;nt++)
        comb[base + nt*16 + l16] = f2b(b2f(hs[base + nt*16 + l16]) + o[nt][r]*f);
    }
  }
}

// ---------------- launch ----------------
extern "C" void kernel_launch(void* const* d_in, const int* in_sizes, int n_in,
                              void* d_out, int out_size, void* d_ws, size_t ws_size,
                              hipStream_t stream)
{
  const float* hid = (const float*)d_in[0];
  const float* Wq  = (const float*)d_in[1];
  const float* Wk  = (const float*)d_in[2];
  const float* Wv  = (const float*)d_in[3];
  const float* Wo  = (const float*)d_in[4];
  const float* bo  = (const float*)d_in[5];
  const float* sks = (const float*)d_in[6];
  const float* svs = (const float*)d_in[7];
  const void*  mid = d_in[8];
  const float* mig = (const float*)d_in[9];
  const void*  scl = d_in[10];

  char* ws = (char*)d_ws;                    // 69.9 MiB total (aliased, stream-ordered)
  float* mk   = (float*)(ws);                // [2][2304]              18432 B
  float* mg   = (float*)(ws + 18432);        // [2][2304]              18432 B
  u32*  mode  = (u32*)(ws + 36864);          // 256 B
  u16*  WT    = (u16*)(ws + 40960);          // 4 x 1280x1280 bf16  13107200 B
  u16*  slotA = (u16*)(ws + 13148160);       // hidB; later sksB (unpadded)       11796480
  u16*  q     = (u16*)(ws + 25534464);       // [16][2304][160] (pre-scaled)      11796480
  u16*  slotB = (u16*)(ws + 37330944);       // k (unpadded); later comb          11796480
  u16*  vt    = (u16*)(ws + 49717248);       // v^T; later vst                    11796480
  u16*  hsB   = (u16*)(ws + 61513728);       // self-attn out bf16                11796480

  maskdet     <<<dim3(1),       256, 0, stream>>>((const u32*)mid, mode);
  maskprep    <<<dim3(18),      256, 0, stream>>>(mid, mig, mk, mg, mode);
  transpose_w <<<dim3(40,40,4), 256, 0, stream>>>(Wq, Wk, Wv, Wo, WT);
  conv        <<<dim3(2880),    256, 0, stream>>>(hid, slotA, 5898240);            // hidB
  gemm128     <<<dim3(36,10,3), 256, 0, stream>>>(slotA, WT, q, slotB, vt, nullptr, nullptr, 0);
  conv        <<<dim3(2880),    256, 0, stream>>>(sks, slotA, 5898240);            // hidB dead -> sksB
  attn        <<<dim3(36,16),   256, 0, stream>>>(q, slotB, vt, nullptr, nullptr, hsB, nullptr, scl, 0);
  transpose_vs<<<dim3(72,5,16), 256, 0, stream>>>(svs, vt);                        // vt dead -> vst
  attn        <<<dim3(36,16),   256, 0, stream>>>(q, slotA, vt, mk, mg, hsB, slotB, scl, 1); // k dead -> comb
  gemm128     <<<dim3(36,10,1), 256, 0, stream>>>(slotB, WT + (size_t)3*1280*1280,
                                                  nullptr, nullptr, nullptr, (float*)d_out, bo, 1);
}

// Round 2
// 827.239 us; speedup vs baseline: 1.4022x; 1.4022x over previous
//
#include <hip/hip_runtime.h>

// Problem: B=2, S=2304, C=1280, NH=8, DH=160, MH=64, SR=48, BH=16
// R7: 957us (attn 2x360, LDS K-stage but DMA drained every iter, naked latency).
// R8: 1160us REGRESSION - K direct from global = 4x K traffic + global latency
//     on the QK^T chain (MfmaUtil 4.7%, WRITE_SIZE 3x from L2 thrash).
// R9: K back in LDS via global_load_lds DMA, now DOUBLE-BUFFERED: DMA for tile
//     kc+1 issued at top of iter kc; the single end-of-iter __syncthreads()
//     (built-in vmcnt(0) drain) lands after a full iter of compute -> DMA
//     latency fully hidden, 1 barrier/iter. Keep R8's DPP softmax + mask
//     prefetch + pre-scaled Q. New: XCD-aware block remap (XCD c owns bh
//     {2c,2c+1}, K+V ~3MB fits 4MB L2) to kill the 3x L2 overfetch.

typedef unsigned short u16;
typedef unsigned int   u32;
typedef unsigned char  u8;
typedef __attribute__((ext_vector_type(8))) short bf16x8;   // 8 bf16 = 4 VGPRs
typedef __attribute__((ext_vector_type(4))) float f32x4;

#define MFMA16(a,b,c) __builtin_amdgcn_mfma_f32_16x16x32_bf16((a),(b),(c),0,0,0)
#define INVS 0.07905694150420949f                 // 1/sqrt(160)
#define KPAD 168                                  // K row stride (u16): 84 dw -> b128 reads at bank floor

typedef const __attribute__((address_space(1))) void gvoid;
typedef __attribute__((address_space(3))) void lvoid;
#define GLD16(gp, lp) __builtin_amdgcn_global_load_lds((gvoid*)(gp), (lvoid*)(lp), 16, 0, 0)

__device__ __forceinline__ u16 f2b(float f) {            // fp32 -> bf16 RNE
  u32 u = __float_as_uint(f);
  return (u16)((u + 0x7fffu + ((u >> 16) & 1u)) >> 16);
}
__device__ __forceinline__ float b2f(u16 v) { return __uint_as_float(((u32)v) << 16); }

// DPP reduction over a 16-lane row (exactly our l16 domain = one DPP row):
// quad_perm(1,0,3,2)=0xB1, quad_perm(2,3,0,1)=0x4E, row_half_mirror=0x141, row_mirror=0x140
#define DPPF(x, ctrl) __int_as_float(__builtin_amdgcn_update_dpp(0, __float_as_int(x), (ctrl), 0xf, 0xf, true))
__device__ __forceinline__ float row_max16(float x) {
  x = fmaxf(x, DPPF(x, 0xB1));
  x = fmaxf(x, DPPF(x, 0x4E));
  x = fmaxf(x, DPPF(x, 0x141));
  x = fmaxf(x, DPPF(x, 0x140));
  return x;
}
__device__ __forceinline__ float row_sum16(float x) {
  x += DPPF(x, 0xB1);
  x += DPPF(x, 0x4E);
  x += DPPF(x, 0x141);
  x += DPPF(x, 0x140);
  return x;
}

// ---------------- mask-mode detector: 0=i32, 1=u8, 2=bf16, 3=f32 ----------------
__global__ __launch_bounds__(256) void maskdet(const u32* __restrict__ mid, u32* mode)
{
  __shared__ int a0, a1, a2, a3;
  int tid = threadIdx.x;
  if (tid == 0) { a0 = 1; a1 = 1; a2 = 1; a3 = 0; }
  __syncthreads();
  #pragma unroll
  for (int j = 0; j < 4; j++) {
    u32 w = mid[tid*4 + j];                      // first 4 KiB, in-bounds for all dtypes
    if (w > 1u)                      atomicAnd(&a0, 0);  // not i32 bools
    if (w & 0xFEFEFEFEu)             atomicAnd(&a1, 0);  // not u8 bools
    if (w != 0u && w != 0x3F800000u) atomicAnd(&a2, 0);  // not f32 {0,1}
    if ((w & 0xFFFFu) == 0x3F80u)    atomicOr(&a3, 1);   // bf16 1.0 in low half
  }
  __syncthreads();
  if (tid == 0) mode[0] = a0 ? 0u : (a1 ? 1u : (a3 ? 2u : (a2 ? 3u : 0u)));
}

// ---------------- nearest-downsample masks 64x64 -> 48x48 flattened to S ----------------
__global__ void maskprep(const void* mid, const float* __restrict__ mig_in,
                         float* __restrict__ mk, float* __restrict__ mg, const u32* mode)
{
  int j = blockIdx.x*256 + threadIdx.x;
  if (j >= 2*2304) return;
  u32 md = mode[0];
  int b = j / 2304, s = j % 2304;
  int i = s / 48, jj = s % 48;
  int ih = (i*4)/3, iw = (jj*4)/3;        // arange(48)*64//48
  int src = b*4096 + ih*64 + iw;
  bool on;
  if      (md == 0) on = ((const int*)mid)[src] != 0;
  else if (md == 1) on = ((const u8*)mid)[src]  != 0;
  else if (md == 2) on = ((const u16*)mid)[src] != 0;
  else              on = ((const float*)mid)[src] != 0.0f;
  mk[j] = on ? 1.0f : 0.0f;
  mg[j] = mig_in[src];                     // mask_ig is fp32
}

// ---------------- transpose weights: fp32 W[k][n] -> bf16 WT[n][k], 4 matrices --------------
__global__ __launch_bounds__(256) void transpose_w(
    const float* __restrict__ W0, const float* __restrict__ W1,
    const float* __restrict__ W2, const float* __restrict__ W3, u16* __restrict__ WT)
{
  __shared__ u16 t[32][33];
  int z = blockIdx.z;
  const float* s = (z==0)?W0:(z==1)?W1:(z==2)?W2:W3;
  u16* d = WT + (size_t)z*1280*1280;
  int tx = threadIdx.x & 31, ty = (threadIdx.x >> 5) * 4;
  int x = blockIdx.x*32 + tx;          // src col (n)
  int y = blockIdx.y*32 + ty;          // src row (k)
  #pragma unroll
  for (int i=0;i<4;i++) t[ty+i][tx] = f2b(s[(size_t)(y+i)*1280 + x]);
  __syncthreads();
  int x2 = blockIdx.y*32 + tx, y2 = blockIdx.x*32 + ty;
  #pragma unroll
  for (int i=0;i<4;i++) d[(size_t)(y2+i)*1280 + x2] = t[tx][ty+i];   // WT[n][k] = W[k][n]
}

// ---------------- convert fp32 -> bf16 (unpadded) ----------------
__global__ __launch_bounds__(256) void conv(const float* __restrict__ src, u16* __restrict__ dst, int n)
{
  for (int i = blockIdx.x*256 + threadIdx.x; i < n; i += gridDim.x*256)
    dst[i] = f2b(src[i]);
}

// ---------------- convert store_ks fp32 [bh][s][160] -> padded bf16 [bh][s][168] ------------
__global__ __launch_bounds__(256) void convK(const float* __restrict__ src, u16* __restrict__ dst)
{
  const int n = 16*2304*KPAD;
  for (int i = blockIdx.x*256 + threadIdx.x; i < n; i += gridDim.x*256) {
    int row = i / KPAD, col = i % KPAD;
    dst[i] = (col < 160) ? f2b(src[(size_t)row*160 + col]) : (u16)0;
  }
}

// ---------------- transpose store_vs fp32 [16][2304][160] -> bf16 vst[16][160][2304] ---------
__global__ __launch_bounds__(256) void transpose_vs(const float* __restrict__ src, u16* __restrict__ dst)
{
  __shared__ u16 t[32][33];
  int z = blockIdx.z;
  u16* d = dst + (size_t)z*160*2304;
  int tx = threadIdx.x & 31, ty = (threadIdx.x >> 5) * 4;
  int r0 = blockIdx.x*32, c0 = blockIdx.y*32;
  #pragma unroll
  for (int i=0;i<4;i++)
    t[ty+i][tx] = f2b(src[((size_t)z*2304 + r0+ty+i)*160 + c0+tx]);
  __syncthreads();
  #pragma unroll
  for (int i=0;i<4;i++) d[(size_t)(c0+ty+i)*2304 + r0+tx] = t[tx][ty+i]; // d[c][r] = s[r][c]
}

// ---------------- GEMM: 128x128 tile, BK=32, 4 waves (2x2), 16x16x32 MFMA ----------------
// kind 0: A=hidB, BT=WT[z]; z=0->q*INVS [bh][s][160], z=1->k PADDED [bh][s][168], z=2->v^T [bh][d][s]
// kind 1: A=comb, BT=WoT;   out = A@Wo + bias -> fp32 d_out
__global__ __launch_bounds__(256, 2) void gemm128(
    const u16* __restrict__ A, const u16* __restrict__ BT,
    u16* __restrict__ dq, u16* __restrict__ dk, u16* __restrict__ dvt,
    float* __restrict__ dout, const float* __restrict__ bias, int kind)
{
  __shared__ __align__(16) u16 As[128*40];   // pad 32->40: 80B stride breaks conflicts
  __shared__ __align__(16) u16 Bs[128*40];
  int tid = threadIdx.x;
  int m0 = blockIdx.x*128, n0 = blockIdx.y*128;
  int z = blockIdx.z;
  const u16* Bt = BT + (size_t)z*1280*1280;
  int w = tid>>6, lane = tid&63, quad = lane>>4, l16 = lane&15;
  int wm = w&1, wn = w>>1;
  int arow = tid>>1, acg = (tid&1)*16;
  f32x4 zero = {0.f,0.f,0.f,0.f};
  f32x4 acc[4][4];
  #pragma unroll
  for (int a=0;a<4;a++) { acc[a][0]=zero; acc[a][1]=zero; acc[a][2]=zero; acc[a][3]=zero; }
  const u16* ga = A  + (size_t)(m0+arow)*1280 + acg;
  const u16* gb = Bt + (size_t)(n0+arow)*1280 + acg;
  for (int k0 = 0; k0 < 1280; k0 += 32) {
    uint4 a0 = *(const uint4*)(ga + k0);
    uint4 a1 = *(const uint4*)(ga + k0 + 8);
    uint4 b0 = *(const uint4*)(gb + k0);
    uint4 b1 = *(const uint4*)(gb + k0 + 8);
    __syncthreads();
    *(uint4*)&As[arow*40 + acg]     = a0;
    *(uint4*)&As[arow*40 + acg + 8] = a1;
    *(uint4*)&Bs[arow*40 + acg]     = b0;
    *(uint4*)&Bs[arow*40 + acg + 8] = b1;
    __syncthreads();
    bf16x8 af[4], bfr[4];
    #pragma unroll
    for (int mt=0; mt<4; mt++) af[mt]  = *(const bf16x8*)&As[(wm*64+mt*16+l16)*40 + quad*8];
    #pragma unroll
    for (int nt=0; nt<4; nt++) bfr[nt] = *(const bf16x8*)&Bs[(wn*64+nt*16+l16)*40 + quad*8];
    #pragma unroll
    for (int mt=0; mt<4; mt++)
      #pragma unroll
      for (int nt=0; nt<4; nt++)
        acc[mt][nt] = MFMA16(af[mt], bfr[nt], acc[mt][nt]);
  }
  #pragma unroll
  for (int mt=0; mt<4; mt++) {
    int r0g = m0 + wm*64 + mt*16 + quad*4;          // 4 consecutive rows (reg 0..3)
    #pragma unroll
    for (int nt=0; nt<4; nt++) {
      int col = n0 + wn*64 + nt*16 + l16;
      if (kind == 1) {
        float bi = bias[col];
        #pragma unroll
        for (int r=0;r<4;r++) dout[(size_t)(r0g+r)*1280 + col] = acc[mt][nt][r] + bi;
      } else {
        int h = col/160, d = col%160;
        if (z == 2) {                               // v -> [bh][d][s], s consecutive
          int b = r0g/2304, s0 = r0g%2304;
          size_t base = ((size_t)((b*8+h)*160 + d))*2304 + s0;
          ushort4 pk;
          pk.x = f2b(acc[mt][nt][0]); pk.y = f2b(acc[mt][nt][1]);
          pk.z = f2b(acc[mt][nt][2]); pk.w = f2b(acc[mt][nt][3]);
          *(ushort4*)&dvt[base] = pk;
        } else {
          #pragma unroll
          for (int r=0;r<4;r++) {
            int rg = r0g + r;
            int b = rg/2304, s = rg%2304;
            if (z == 0) dq[((size_t)(b*8+h)*2304 + s)*160  + d] = f2b(acc[mt][nt][r] * INVS);
            else        dk[((size_t)(b*8+h)*2304 + s)*KPAD + d] = f2b(acc[mt][nt][r]);
          }
        }
      }
    }
  }
}

// ---------------- Attention (flash-style, online softmax). ----------------
// ip=0: self -> hs (bf16). ip=1: keys=sksP, V=vst, per-key mask, combine -> comb bf16.
// K staged into LDS via global_load_lds DMA (padded rows -> contiguous 21504B tiles),
// DOUBLE-BUFFERED: DMA for tile kc+1 issued at top of iter kc; the single
// end-of-iter __syncthreads() (built-in vmcnt(0) drain) lands after a full iter
// of compute -> DMA latency hidden. 1 barrier/iter. Softmax via DPP (VALU pipe).
// V B-frags direct from global (L2-resident after XCD remap). Q pre-scaled.
__global__ __launch_bounds__(256, 3) void attn(
    const u16* __restrict__ qg,   // [16][2304][160], pre-scaled by INVS
    const u16* __restrict__ kg,   // PADDED [16][2304][168]
    const u16* __restrict__ vtg,  // [16][160][2304]
    const float* __restrict__ maskkey, const float* __restrict__ mig,
    u16* __restrict__ hs, u16* __restrict__ comb,
    const void* scaleptr, int ip)
{
  __shared__ __align__(16) u16 Ks[2][64*KPAD];  // 2 x 21504 B double buffer
  __shared__ __align__(16) u16 Ps[4*16*72];     // per-wave P relayout buffer
  // XCD-aware remap: linear dispatch id round-robins XCDs (id%8). Give XCD c
  // bh {2c, 2c+1} so its working set (K 774KB + V 737KB per bh) fits 4MB L2.
  int id = blockIdx.y*36 + blockIdx.x;
  int xc = id & 7, kq = id >> 3;                 // kq in 0..71
  int bh = 2*xc + (kq >= 36 ? 1 : 0);
  int qt = (kq >= 36) ? kq - 36 : kq;
  int tid = threadIdx.x, w = tid>>6, lane = tid&63, quad = lane>>4, l16 = lane&15;
  int q0 = qt*64 + w*16;                         // wave's 16 queries

  const char* kgbytes = (const char*)kg;
  const char* ktile0 = kgbytes + ((size_t)bh*2304)*(KPAD*2);

  // ---- issue DMA for tile 0 immediately (drained by the pre-loop barrier) ----
  {
    const char* tile = ktile0;
    char* dst = (char*)&Ks[0][0];
    int off = w*1024 + lane*16;
    #pragma unroll
    for (int j=0;j<5;j++) GLD16(tile + j*4096 + off, dst + j*4096 + w*1024);
    if (w == 0) GLD16(tile + 20480 + lane*16, dst + 20480);  // 21504-20480 tail
  }

  bf16x8 aq[5];                                // Q frags: A[m=l16][k=quad*8+j], 5 ksteps
  {
    const u16* qrow = qg + ((size_t)bh*2304 + q0 + l16)*160 + quad*8;
    #pragma unroll
    for (int ks=0; ks<5; ks++) aq[ks] = *(const bf16x8*)(qrow + ks*32);
  }
  f32x4 zero = {0.f,0.f,0.f,0.f};
  f32x4 o[10];
  #pragma unroll
  for (int i=0;i<10;i++) o[i] = zero;
  float mrun[4] = {-1e30f,-1e30f,-1e30f,-1e30f};
  float lrun[4] = {0.f,0.f,0.f,0.f};

  const u16* vbase = vtg + ((size_t)bh*160 + l16)*2304 + quad*8;   // + nt*16 rows + key offs

  float mcur[4] = {1.f,1.f,1.f,1.f};
  if (ip) {
    #pragma unroll
    for (int nt=0;nt<4;nt++) mcur[nt] = maskkey[(bh & 1)*2304 + nt*16 + l16];
  }

  __syncthreads();                             // drains own DMA (vmcnt 0) + barrier: Ks[0] ready

  for (int kc = 0; kc < 36; kc++) {
    int cur = kc & 1;

    // ---- issue DMA for NEXT tile into the other buffer (latency hides under compute) ----
    if (kc < 35) {
      const char* tile = ktile0 + (size_t)(kc+1)*64*(KPAD*2);
      char* dst = (char*)&Ks[cur^1][0];
      int off = w*1024 + lane*16;
      #pragma unroll
      for (int j=0;j<5;j++) GLD16(tile + j*4096 + off, dst + j*4096 + w*1024);
      if (w == 0) GLD16(tile + 20480 + lane*16, dst + 20480);
    }

    // ---- prefetch next iteration's mask values (off the score critical path) ----
    float mnxt[4] = {1.f,1.f,1.f,1.f};
    if (ip && kc < 35) {
      #pragma unroll
      for (int nt=0;nt<4;nt++) mnxt[nt] = maskkey[(bh & 1)*2304 + (kc+1)*64 + nt*16 + l16];
    }

    // ---- scores S[16 q][64 keys] = Q K^T (Q pre-scaled), K from LDS ----
    f32x4 sc[4];
    bool keep[4];
    #pragma unroll
    for (int nt=0; nt<4; nt++) {
      f32x4 s = zero;
      #pragma unroll
      for (int ks=0; ks<5; ks++) {
        bf16x8 bk = *(const bf16x8*)&Ks[cur][(nt*16+l16)*KPAD + ks*32 + quad*8];
        s = MFMA16(aq[ks], bk, s);
      }
      keep[nt] = true;
      if (ip && mcur[nt] == 0.0f) {
        keep[nt] = false;
        #pragma unroll
        for (int r=0;r<4;r++) s[r] = -1e30f;
      }
      sc[nt] = s;
    }

    // ---- online softmax per query row (row = quad*4+r), DPP row reductions ----
    float p[4][4];
    #pragma unroll
    for (int r=0;r<4;r++) {
      float mrow = fmaxf(fmaxf(sc[0][r], sc[1][r]), fmaxf(sc[2][r], sc[3][r]));
      mrow = row_max16(mrow);
      float nm = fmaxf(mrun[r], mrow);
      float alpha = __expf(fminf(mrun[r] - nm, 0.f));
      mrun[r] = nm;
      float rs = 0.f;
      #pragma unroll
      for (int nt=0;nt<4;nt++) {
        float e = keep[nt] ? __expf(sc[nt][r] - nm) : 0.f;
        p[nt][r] = e; rs += e;
      }
      rs = row_sum16(rs);
      lrun[r] = lrun[r]*alpha + rs;
      #pragma unroll
      for (int nt2=0; nt2<10; nt2++) o[nt2][r] *= alpha;
    }

    // ---- P: C-layout -> A-layout via per-wave LDS (same-wave dep, compiler waits) ----
    #pragma unroll
    for (int nt=0;nt<4;nt++)
      #pragma unroll
      for (int r=0;r<4;r++)
        Ps[(w*16 + quad*4 + r)*72 + nt*16 + l16] = f2b(p[nt][r]);

    // ---- O += P V, V B-frags straight from global (16B/lane, L2-resident tile) ----
    #pragma unroll
    for (int kb=0; kb<2; kb++) {
      bf16x8 ap = *(const bf16x8*)&Ps[(w*16 + l16)*72 + kb*32 + quad*8];
      #pragma unroll
      for (int nt=0; nt<10; nt++) {
        bf16x8 bv = *(const bf16x8*)(vbase + (size_t)nt*16*2304 + kc*64 + kb*32);
        o[nt] = MFMA16(ap, bv, o[nt]);
      }
    }

    if (ip) {
      #pragma unroll
      for (int nt=0;nt<4;nt++) mcur[nt] = mnxt[nt];
    }

    // ---- single barrier: drains own DMA (next tile ready) + all waves done with cur ----
    __syncthreads();
  }

  // ---- epilogue ----
  int b = bh>>3, h = bh&7;
  float scl = 0.f;
  if (ip) {                                   // scalar dtype self-detect (0.5 decodes both ways)
    u16 v0 = ((const u16*)scaleptr)[0];
    int e = (v0 >> 7) & 0xFF;
    scl = (v0 != 0 && e >= 100 && e <= 133) ? b2f(v0) : ((const float*)scaleptr)[0];
  }
  #pragma unroll
  for (int r=0;r<4;r++) {
    int s = q0 + quad*4 + r;
    float linv = (lrun[r] > 0.f) ? 1.0f/lrun[r] : 0.f;
    size_t base = ((size_t)b*2304 + s)*1280 + h*160;
    if (!ip) {
      #pragma unroll
      for (int nt=0;nt<10;nt++) hs[base + nt*16 + l16] = f2b(o[nt][r]*linv);
    } else {
      float f = mig[b*2304 + s]*scl*linv;    // mig uses TRUE b
      #pragma unroll
      for (int nt=0;nt<10;nt++)
        comb[base + nt*16 + l16] = f2b(b2f(hs[base + nt*16 + l16]) + o[nt][r]*f);
    }
  }
}

// ---------------- launch ----------------
extern "C" void kernel_launch(void* const* d_in, const int* in_sizes, int n_in,
                              void* d_out, int out_size, void* d_ws, size_t ws_size,
                              hipStream_t stream)
{
  const float* hid = (const float*)d_in[0];
  const float* Wq  = (const float*)d_in[1];
  const float* Wk  = (const float*)d_in[2];
  const float* Wv  = (const float*)d_in[3];
  const float* Wo  = (const float*)d_in[4];
  const float* bo  = (const float*)d_in[5];
  const float* sks = (const float*)d_in[6];
  const float* svs = (const float*)d_in[7];
  const void*  mid = d_in[8];
  const float* mig = (const float*)d_in[9];
  const void*  scl = d_in[10];

  char* ws = (char*)d_ws;                    // 69.9 MiB total (aliased, stream-ordered)
  float* mk   = (float*)(ws);                // [2][2304]              18432 B
  float* mg   = (float*)(ws + 18432);        // [2][2304]              18432 B
  u32*  mode  = (u32*)(ws + 36864);          // 256 B
  u16*  WT    = (u16*)(ws + 40960);          // 4 x 1280x1280 bf16  13107200 B
  u16*  slotA = (u16*)(ws + 13148160);       // hidB unpadded; later sksP padded  12386304
  u16*  q     = (u16*)(ws + 25534464);       // [16][2304][160] (pre-scaled)      11796480
  u16*  slotB = (u16*)(ws + 37330944);       // kP padded; later comb             12386304
  u16*  vt    = (u16*)(ws + 49717248);       // v^T; later vst                    11796480
  u16*  hsB   = (u16*)(ws + 61513728);       // self-attn out bf16                11796480

  maskdet     <<<dim3(1),       256, 0, stream>>>((const u32*)mid, mode);
  maskprep    <<<dim3(18),      256, 0, stream>>>(mid, mig, mk, mg, mode);
  transpose_w <<<dim3(40,40,4), 256, 0, stream>>>(Wq, Wk, Wv, Wo, WT);
  conv        <<<dim3(2880),    256, 0, stream>>>(hid, slotA, 5898240);            // hidB
  gemm128     <<<dim3(36,10,3), 256, 0, stream>>>(slotA, WT, q, slotB, vt, nullptr, nullptr, 0);
  convK       <<<dim3(6048),    256, 0, stream>>>(sks, slotA);                     // hidB dead -> sksP
  attn        <<<dim3(36,16),   256, 0, stream>>>(q, slotB, vt, nullptr, nullptr, hsB, nullptr, scl, 0);
  transpose_vs<<<dim3(72,5,16), 256, 0, stream>>>(svs, vt);                        // vt dead -> vst
  attn        <<<dim3(36,16),   256, 0, stream>>>(q, slotA, vt, mk, mg, hsB, slotB, scl, 1); // kP dead -> comb
  gemm128     <<<dim3(36,10,1), 256, 0, stream>>>(slotB, WT + (size_t)3*1280*1280,
                                                  nullptr, nullptr, nullptr, (float*)d_out, bo, 1);
}

// Round 3
// 563.826 us; speedup vs baseline: 2.0573x; 1.4672x over previous
//
#include <hip/hip_runtime.h>

// Problem: B=2, S=2304, C=1280, NH=8, DH=160, MH=64, SR=48, BH=16
// R9: 827us (attn 2x294). XCD remap killed L2 overfetch (FETCH 112->23.5MB),
//     dbuf K-DMA hid K latency. Still latency-bound: MfmaUtil 7.5%, VALU 17%.
// R10 theory: residual stall = per-wave V gathers (20 instr/iter, each touching
//     16 scattered 64B lines; 2 blocks x 20KB tiles thrash 32KB L1 -> every
//     fragment an L2 round trip, limited miss concurrency ~5us/iter).
// R10: stage V tile (160x128B) in LDS once per block via global_load_lds with
//     PER-LANE global source addresses + XOR granule swizzle (slot = g^(d&7))
//     so lane-linear LDS image reads conflict-free as ds_read_b128 (no pad).
//     V single-buffered (covered by QK^T+softmax); K dbuf DMA moved after the
//     mid barrier (covered by PV). 2 barriers/iter, both with compute to hide.

typedef unsigned short u16;
typedef unsigned int   u32;
typedef unsigned char  u8;
typedef __attribute__((ext_vector_type(8))) short bf16x8;   // 8 bf16 = 4 VGPRs
typedef __attribute__((ext_vector_type(4))) float f32x4;

#define MFMA16(a,b,c) __builtin_amdgcn_mfma_f32_16x16x32_bf16((a),(b),(c),0,0,0)
#define INVS 0.07905694150420949f                 // 1/sqrt(160)
#define KPAD 168                                  // K row stride (u16): 84 dw -> b128 reads at bank floor

typedef const __attribute__((address_space(1))) void gvoid;
typedef __attribute__((address_space(3))) void lvoid;
#define GLD16(gp, lp) __builtin_amdgcn_global_load_lds((gvoid*)(gp), (lvoid*)(lp), 16, 0, 0)

__device__ __forceinline__ u16 f2b(float f) {            // fp32 -> bf16 RNE
  u32 u = __float_as_uint(f);
  return (u16)((u + 0x7fffu + ((u >> 16) & 1u)) >> 16);
}
__device__ __forceinline__ float b2f(u16 v) { return __uint_as_float(((u32)v) << 16); }

// DPP reduction over a 16-lane row (exactly our l16 domain = one DPP row):
// quad_perm(1,0,3,2)=0xB1, quad_perm(2,3,0,1)=0x4E, row_half_mirror=0x141, row_mirror=0x140
#define DPPF(x, ctrl) __int_as_float(__builtin_amdgcn_update_dpp(0, __float_as_int(x), (ctrl), 0xf, 0xf, true))
__device__ __forceinline__ float row_max16(float x) {
  x = fmaxf(x, DPPF(x, 0xB1));
  x = fmaxf(x, DPPF(x, 0x4E));
  x = fmaxf(x, DPPF(x, 0x141));
  x = fmaxf(x, DPPF(x, 0x140));
  return x;
}
__device__ __forceinline__ float row_sum16(float x) {
  x += DPPF(x, 0xB1);
  x += DPPF(x, 0x4E);
  x += DPPF(x, 0x141);
  x += DPPF(x, 0x140);
  return x;
}

// ---------------- mask-mode detector: 0=i32, 1=u8, 2=bf16, 3=f32 ----------------
__global__ __launch_bounds__(256) void maskdet(const u32* __restrict__ mid, u32* mode)
{
  __shared__ int a0, a1, a2, a3;
  int tid = threadIdx.x;
  if (tid == 0) { a0 = 1; a1 = 1; a2 = 1; a3 = 0; }
  __syncthreads();
  #pragma unroll
  for (int j = 0; j < 4; j++) {
    u32 w = mid[tid*4 + j];                      // first 4 KiB, in-bounds for all dtypes
    if (w > 1u)                      atomicAnd(&a0, 0);  // not i32 bools
    if (w & 0xFEFEFEFEu)             atomicAnd(&a1, 0);  // not u8 bools
    if (w != 0u && w != 0x3F800000u) atomicAnd(&a2, 0);  // not f32 {0,1}
    if ((w & 0xFFFFu) == 0x3F80u)    atomicOr(&a3, 1);   // bf16 1.0 in low half
  }
  __syncthreads();
  if (tid == 0) mode[0] = a0 ? 0u : (a1 ? 1u : (a3 ? 2u : (a2 ? 3u : 0u)));
}

// ---------------- nearest-downsample masks 64x64 -> 48x48 flattened to S ----------------
__global__ void maskprep(const void* mid, const float* __restrict__ mig_in,
                         float* __restrict__ mk, float* __restrict__ mg, const u32* mode)
{
  int j = blockIdx.x*256 + threadIdx.x;
  if (j >= 2*2304) return;
  u32 md = mode[0];
  int b = j / 2304, s = j % 2304;
  int i = s / 48, jj = s % 48;
  int ih = (i*4)/3, iw = (jj*4)/3;        // arange(48)*64//48
  int src = b*4096 + ih*64 + iw;
  bool on;
  if      (md == 0) on = ((const int*)mid)[src] != 0;
  else if (md == 1) on = ((const u8*)mid)[src]  != 0;
  else if (md == 2) on = ((const u16*)mid)[src] != 0;
  else              on = ((const float*)mid)[src] != 0.0f;
  mk[j] = on ? 1.0f : 0.0f;
  mg[j] = mig_in[src];                     // mask_ig is fp32
}

// ---------------- transpose weights: fp32 W[k][n] -> bf16 WT[n][k], 4 matrices --------------
__global__ __launch_bounds__(256) void transpose_w(
    const float* __restrict__ W0, const float* __restrict__ W1,
    const float* __restrict__ W2, const float* __restrict__ W3, u16* __restrict__ WT)
{
  __shared__ u16 t[32][33];
  int z = blockIdx.z;
  const float* s = (z==0)?W0:(z==1)?W1:(z==2)?W2:W3;
  u16* d = WT + (size_t)z*1280*1280;
  int tx = threadIdx.x & 31, ty = (threadIdx.x >> 5) * 4;
  int x = blockIdx.x*32 + tx;          // src col (n)
  int y = blockIdx.y*32 + ty;          // src row (k)
  #pragma unroll
  for (int i=0;i<4;i++) t[ty+i][tx] = f2b(s[(size_t)(y+i)*1280 + x]);
  __syncthreads();
  int x2 = blockIdx.y*32 + tx, y2 = blockIdx.x*32 + ty;
  #pragma unroll
  for (int i=0;i<4;i++) d[(size_t)(y2+i)*1280 + x2] = t[tx][ty+i];   // WT[n][k] = W[k][n]
}

// ---------------- convert fp32 -> bf16 (unpadded) ----------------
__global__ __launch_bounds__(256) void conv(const float* __restrict__ src, u16* __restrict__ dst, int n)
{
  for (int i = blockIdx.x*256 + threadIdx.x; i < n; i += gridDim.x*256)
    dst[i] = f2b(src[i]);
}

// ---------------- convert store_ks fp32 [bh][s][160] -> padded bf16 [bh][s][168] ------------
__global__ __launch_bounds__(256) void convK(const float* __restrict__ src, u16* __restrict__ dst)
{
  const int n = 16*2304*KPAD;
  for (int i = blockIdx.x*256 + threadIdx.x; i < n; i += gridDim.x*256) {
    int row = i / KPAD, col = i % KPAD;
    dst[i] = (col < 160) ? f2b(src[(size_t)row*160 + col]) : (u16)0;
  }
}

// ---------------- transpose store_vs fp32 [16][2304][160] -> bf16 vst[16][160][2304] ---------
__global__ __launch_bounds__(256) void transpose_vs(const float* __restrict__ src, u16* __restrict__ dst)
{
  __shared__ u16 t[32][33];
  int z = blockIdx.z;
  u16* d = dst + (size_t)z*160*2304;
  int tx = threadIdx.x & 31, ty = (threadIdx.x >> 5) * 4;
  int r0 = blockIdx.x*32, c0 = blockIdx.y*32;
  #pragma unroll
  for (int i=0;i<4;i++)
    t[ty+i][tx] = f2b(src[((size_t)z*2304 + r0+ty+i)*160 + c0+tx]);
  __syncthreads();
  #pragma unroll
  for (int i=0;i<4;i++) d[(size_t)(c0+ty+i)*2304 + r0+tx] = t[tx][ty+i]; // d[c][r] = s[r][c]
}

// ---------------- GEMM: 128x128 tile, BK=32, 4 waves (2x2), 16x16x32 MFMA ----------------
// kind 0: A=hidB, BT=WT[z]; z=0->q*INVS [bh][s][160], z=1->k PADDED [bh][s][168], z=2->v^T [bh][d][s]
// kind 1: A=comb, BT=WoT;   out = A@Wo + bias -> fp32 d_out
__global__ __launch_bounds__(256, 2) void gemm128(
    const u16* __restrict__ A, const u16* __restrict__ BT,
    u16* __restrict__ dq, u16* __restrict__ dk, u16* __restrict__ dvt,
    float* __restrict__ dout, const float* __restrict__ bias, int kind)
{
  __shared__ __align__(16) u16 As[128*40];   // pad 32->40: 80B stride breaks conflicts
  __shared__ __align__(16) u16 Bs[128*40];
  int tid = threadIdx.x;
  int m0 = blockIdx.x*128, n0 = blockIdx.y*128;
  int z = blockIdx.z;
  const u16* Bt = BT + (size_t)z*1280*1280;
  int w = tid>>6, lane = tid&63, quad = lane>>4, l16 = lane&15;
  int wm = w&1, wn = w>>1;
  int arow = tid>>1, acg = (tid&1)*16;
  f32x4 zero = {0.f,0.f,0.f,0.f};
  f32x4 acc[4][4];
  #pragma unroll
  for (int a=0;a<4;a++) { acc[a][0]=zero; acc[a][1]=zero; acc[a][2]=zero; acc[a][3]=zero; }
  const u16* ga = A  + (size_t)(m0+arow)*1280 + acg;
  const u16* gb = Bt + (size_t)(n0+arow)*1280 + acg;
  for (int k0 = 0; k0 < 1280; k0 += 32) {
    uint4 a0 = *(const uint4*)(ga + k0);
    uint4 a1 = *(const uint4*)(ga + k0 + 8);
    uint4 b0 = *(const uint4*)(gb + k0);
    uint4 b1 = *(const uint4*)(gb + k0 + 8);
    __syncthreads();
    *(uint4*)&As[arow*40 + acg]     = a0;
    *(uint4*)&As[arow*40 + acg + 8] = a1;
    *(uint4*)&Bs[arow*40 + acg]     = b0;
    *(uint4*)&Bs[arow*40 + acg + 8] = b1;
    __syncthreads();
    bf16x8 af[4], bfr[4];
    #pragma unroll
    for (int mt=0; mt<4; mt++) af[mt]  = *(const bf16x8*)&As[(wm*64+mt*16+l16)*40 + quad*8];
    #pragma unroll
    for (int nt=0; nt<4; nt++) bfr[nt] = *(const bf16x8*)&Bs[(wn*64+nt*16+l16)*40 + quad*8];
    #pragma unroll
    for (int mt=0; mt<4; mt++)
      #pragma unroll
      for (int nt=0; nt<4; nt++)
        acc[mt][nt] = MFMA16(af[mt], bfr[nt], acc[mt][nt]);
  }
  #pragma unroll
  for (int mt=0; mt<4; mt++) {
    int r0g = m0 + wm*64 + mt*16 + quad*4;          // 4 consecutive rows (reg 0..3)
    #pragma unroll
    for (int nt=0; nt<4; nt++) {
      int col = n0 + wn*64 + nt*16 + l16;
      if (kind == 1) {
        float bi = bias[col];
        #pragma unroll
        for (int r=0;r<4;r++) dout[(size_t)(r0g+r)*1280 + col] = acc[mt][nt][r] + bi;
      } else {
        int h = col/160, d = col%160;
        if (z == 2) {                               // v -> [bh][d][s], s consecutive
          int b = r0g/2304, s0 = r0g%2304;
          size_t base = ((size_t)((b*8+h)*160 + d))*2304 + s0;
          ushort4 pk;
          pk.x = f2b(acc[mt][nt][0]); pk.y = f2b(acc[mt][nt][1]);
          pk.z = f2b(acc[mt][nt][2]); pk.w = f2b(acc[mt][nt][3]);
          *(ushort4*)&dvt[base] = pk;
        } else {
          #pragma unroll
          for (int r=0;r<4;r++) {
            int rg = r0g + r;
            int b = rg/2304, s = rg%2304;
            if (z == 0) dq[((size_t)(b*8+h)*2304 + s)*160  + d] = f2b(acc[mt][nt][r] * INVS);
            else        dk[((size_t)(b*8+h)*2304 + s)*KPAD + d] = f2b(acc[mt][nt][r]);
          }
        }
      }
    }
  }
}

// ---------------- Attention (flash-style, online softmax). ----------------
// ip=0: self -> hs (bf16). ip=1: keys=sksP, V=vst, per-key mask, combine -> comb bf16.
// K: LDS double-buffered DMA (padded global rows -> contiguous 21504B tiles).
// V: LDS single-buffered DMA with PER-LANE global sources + XOR granule swizzle
//    (row d, 16B granule g stored at slot g^(d&7) -> ds_read_b128 at bank floor).
// Loop: [issue V(kc) DMA] QK^T/softmax/Ps  |bar#1: V ready|  [issue K(kc+1) DMA]
//       PV from LDS  |bar#2: K-next ready, Vs consumed|.  Both drains covered.
__global__ __launch_bounds__(256, 2) void attn(
    const u16* __restrict__ qg,   // [16][2304][160], pre-scaled by INVS
    const u16* __restrict__ kg,   // PADDED [16][2304][168]
    const u16* __restrict__ vtg,  // [16][160][2304]
    const float* __restrict__ maskkey, const float* __restrict__ mig,
    u16* __restrict__ hs, u16* __restrict__ comb,
    const void* scaleptr, int ip)
{
  __shared__ __align__(16) u16 Ks[2][64*KPAD];  // 2 x 21504 B double buffer
  __shared__ __align__(16) u16 Vs[160*64];      // 20480 B, XOR-swizzled granules
  __shared__ __align__(16) u16 Ps[4*16*72];     // per-wave P relayout buffer
  // XCD-aware remap: linear dispatch id round-robins XCDs (id%8). Give XCD c
  // bh {2c, 2c+1} so its working set (K 774KB + V 737KB per bh) fits 4MB L2.
  int id = blockIdx.y*36 + blockIdx.x;
  int xc = id & 7, kq = id >> 3;                 // kq in 0..71
  int bh = 2*xc + (kq >= 36 ? 1 : 0);
  int qt = (kq >= 36) ? kq - 36 : kq;
  int tid = threadIdx.x, w = tid>>6, lane = tid&63, quad = lane>>4, l16 = lane&15;
  int q0 = qt*64 + w*16;                         // wave's 16 queries

  const char* kgbytes = (const char*)kg;
  const char* ktile0 = kgbytes + ((size_t)bh*2304)*(KPAD*2);
  const char* vbytes = (const char*)vtg + ((size_t)bh*160)*2304*2;  // V^T slice base

  // ---- issue DMA for K tile 0 immediately (drained by the pre-loop barrier) ----
  {
    const char* tile = ktile0;
    char* dst = (char*)&Ks[0][0];
    int off = w*1024 + lane*16;
    #pragma unroll
    for (int j=0;j<5;j++) GLD16(tile + j*4096 + off, dst + j*4096 + w*1024);
    if (w == 0) GLD16(tile + 20480 + lane*16, dst + 20480);  // 21504-20480 tail
  }

  bf16x8 aq[5];                                // Q frags: A[m=l16][k=quad*8+j], 5 ksteps
  {
    const u16* qrow = qg + ((size_t)bh*2304 + q0 + l16)*160 + quad*8;
    #pragma unroll
    for (int ks=0; ks<5; ks++) aq[ks] = *(const bf16x8*)(qrow + ks*32);
  }
  f32x4 zero = {0.f,0.f,0.f,0.f};
  f32x4 o[10];
  #pragma unroll
  for (int i=0;i<10;i++) o[i] = zero;
  float mrun[4] = {-1e30f,-1e30f,-1e30f,-1e30f};
  float lrun[4] = {0.f,0.f,0.f,0.f};

  // V DMA lane geometry: instr j covers d-rows [j*8, j*8+8), 8 lanes per row.
  // Lane l fetches global granule ((l&7)^(l>>3)) of row j*8+(l>>3); LDS image
  // then has granule g of row d at byte d*128 + (g^(d&7))*16.
  int vrowl = lane>>3;                          // local d row 0..7
  int vgsw  = ((lane&7) ^ vrowl) << 4;          // swizzled source byte offset

  float mcur[4] = {1.f,1.f,1.f,1.f};
  if (ip) {
    #pragma unroll
    for (int nt=0;nt<4;nt++) mcur[nt] = maskkey[(bh & 1)*2304 + nt*16 + l16];
  }

  __syncthreads();                             // drains K0 DMA + Q loads; Ks[0] ready

  for (int kc = 0; kc < 36; kc++) {
    int cur = kc & 1;

    // ---- issue V(kc) DMA: 20 instrs/block (5 per wave), per-lane swizzled src ----
    {
      const char* vsrc = vbytes + (size_t)kc*128;     // key-col offset kc*64 keys *2B
      #pragma unroll
      for (int j5=0;j5<5;j5++) {
        int j = w*5 + j5;
        GLD16(vsrc + (size_t)(j*8 + vrowl)*4608 + vgsw, (char*)Vs + j*1024);
      }
    }

    // ---- prefetch next iteration's mask values (off the score critical path) ----
    float mnxt[4] = {1.f,1.f,1.f,1.f};
    if (ip && kc < 35) {
      #pragma unroll
      for (int nt=0;nt<4;nt++) mnxt[nt] = maskkey[(bh & 1)*2304 + (kc+1)*64 + nt*16 + l16];
    }

    // ---- scores S[16 q][64 keys] = Q K^T (Q pre-scaled), K from LDS ----
    f32x4 sc[4];
    bool keep[4];
    #pragma unroll
    for (int nt=0; nt<4; nt++) {
      f32x4 s = zero;
      #pragma unroll
      for (int ks=0; ks<5; ks++) {
        bf16x8 bk = *(const bf16x8*)&Ks[cur][(nt*16+l16)*KPAD + ks*32 + quad*8];
        s = MFMA16(aq[ks], bk, s);
      }
      keep[nt] = true;
      if (ip && mcur[nt] == 0.0f) {
        keep[nt] = false;
        #pragma unroll
        for (int r=0;r<4;r++) s[r] = -1e30f;
      }
      sc[nt] = s;
    }

    // ---- online softmax per query row (row = quad*4+r), DPP row reductions ----
    float p[4][4];
    #pragma unroll
    for (int r=0;r<4;r++) {
      float mrow = fmaxf(fmaxf(sc[0][r], sc[1][r]), fmaxf(sc[2][r], sc[3][r]));
      mrow = row_max16(mrow);
      float nm = fmaxf(mrun[r], mrow);
      float alpha = __expf(fminf(mrun[r] - nm, 0.f));
      mrun[r] = nm;
      float rs = 0.f;
      #pragma unroll
      for (int nt=0;nt<4;nt++) {
        float e = keep[nt] ? __expf(sc[nt][r] - nm) : 0.f;
        p[nt][r] = e; rs += e;
      }
      rs = row_sum16(rs);
      lrun[r] = lrun[r]*alpha + rs;
      #pragma unroll
      for (int nt2=0; nt2<10; nt2++) o[nt2][r] *= alpha;
    }

    // ---- P: C-layout -> A-layout via per-wave LDS (same-wave dep, compiler waits) ----
    #pragma unroll
    for (int nt=0;nt<4;nt++)
      #pragma unroll
      for (int r=0;r<4;r++)
        Ps[(w*16 + quad*4 + r)*72 + nt*16 + l16] = f2b(p[nt][r]);

    __syncthreads();                           // bar#1: V(kc) DMA drained -> Vs valid

    // ---- issue K(kc+1) DMA into the other buffer (drains at bar#2, hidden by PV) ----
    if (kc < 35) {
      const char* tile = ktile0 + (size_t)(kc+1)*64*(KPAD*2);
      char* dst = (char*)&Ks[cur^1][0];
      int off = w*1024 + lane*16;
      #pragma unroll
      for (int j=0;j<5;j++) GLD16(tile + j*4096 + off, dst + j*4096 + w*1024);
      if (w == 0) GLD16(tile + 20480 + lane*16, dst + 20480);
    }

    // ---- O += P V, V B-frags from LDS (XOR-swizzled, bank-floor b128 reads) ----
    #pragma unroll
    for (int kb=0; kb<2; kb++) {
      bf16x8 ap = *(const bf16x8*)&Ps[(w*16 + l16)*72 + kb*32 + quad*8];
      #pragma unroll
      for (int nt=0; nt<10; nt++) {
        int d = nt*16 + l16;
        bf16x8 bv = *(const bf16x8*)((const char*)Vs + d*128 + (((kb*4 + quad) ^ (l16 & 7)) << 4));
        o[nt] = MFMA16(ap, bv, o[nt]);
      }
    }

    if (ip) {
      #pragma unroll
      for (int nt=0;nt<4;nt++) mcur[nt] = mnxt[nt];
    }

    __syncthreads();                           // bar#2: K-next drained; Vs consumed by all
  }

  // ---- epilogue ----
  int b = bh>>3, h = bh&7;
  float scl = 0.f;
  if (ip) {                                   // scalar dtype self-detect (0.5 decodes both ways)
    u16 v0 = ((const u16*)scaleptr)[0];
    int e = (v0 >> 7) & 0xFF;
    scl = (v0 != 0 && e >= 100 && e <= 133) ? b2f(v0) : ((const float*)scaleptr)[0];
  }
  #pragma unroll
  for (int r=0;r<4;r++) {
    int s = q0 + quad*4 + r;
    float linv = (lrun[r] > 0.f) ? 1.0f/lrun[r] : 0.f;
    size_t base = ((size_t)b*2304 + s)*1280 + h*160;
    if (!ip) {
      #pragma unroll
      for (int nt=0;nt<10;nt++) hs[base + nt*16 + l16] = f2b(o[nt][r]*linv);
    } else {
      float f = mig[b*2304 + s]*scl*linv;    // mig uses TRUE b
      #pragma unroll
      for (int nt=0;nt<10;nt++)
        comb[base + nt*16 + l16] = f2b(b2f(hs[base + nt*16 + l16]) + o[nt][r]*f);
    }
  }
}

// ---------------- launch ----------------
extern "C" void kernel_launch(void* const* d_in, const int* in_sizes, int n_in,
                              void* d_out, int out_size, void* d_ws, size_t ws_size,
                              hipStream_t stream)
{
  const float* hid = (const float*)d_in[0];
  const float* Wq  = (const float*)d_in[1];
  const float* Wk  = (const float*)d_in[2];
  const float* Wv  = (const float*)d_in[3];
  const float* Wo  = (const float*)d_in[4];
  const float* bo  = (const float*)d_in[5];
  const float* sks = (const float*)d_in[6];
  const float* svs = (const float*)d_in[7];
  const void*  mid = d_in[8];
  const float* mig = (const float*)d_in[9];
  const void*  scl = d_in[10];

  char* ws = (char*)d_ws;                    // 69.9 MiB total (aliased, stream-ordered)
  float* mk   = (float*)(ws);                // [2][2304]              18432 B
  float* mg   = (float*)(ws + 18432);        // [2][2304]              18432 B
  u32*  mode  = (u32*)(ws + 36864);          // 256 B
  u16*  WT    = (u16*)(ws + 40960);          // 4 x 1280x1280 bf16  13107200 B
  u16*  slotA = (u16*)(ws + 13148160);       // hidB unpadded; later sksP padded  12386304
  u16*  q     = (u16*)(ws + 25534464);       // [16][2304][160] (pre-scaled)      11796480
  u16*  slotB = (u16*)(ws + 37330944);       // kP padded; later comb             12386304
  u16*  vt    = (u16*)(ws + 49717248);       // v^T; later vst                    11796480
  u16*  hsB   = (u16*)(ws + 61513728);       // self-attn out bf16                11796480

  maskdet     <<<dim3(1),       256, 0, stream>>>((const u32*)mid, mode);
  maskprep    <<<dim3(18),      256, 0, stream>>>(mid, mig, mk, mg, mode);
  transpose_w <<<dim3(40,40,4), 256, 0, stream>>>(Wq, Wk, Wv, Wo, WT);
  conv        <<<dim3(2880),    256, 0, stream>>>(hid, slotA, 5898240);            // hidB
  gemm128     <<<dim3(36,10,3), 256, 0, stream>>>(slotA, WT, q, slotB, vt, nullptr, nullptr, 0);
  convK       <<<dim3(6048),    256, 0, stream>>>(sks, slotA);                     // hidB dead -> sksP
  attn        <<<dim3(36,16),   256, 0, stream>>>(q, slotB, vt, nullptr, nullptr, hsB, nullptr, scl, 0);
  transpose_vs<<<dim3(72,5,16), 256, 0, stream>>>(svs, vt);                        // vt dead -> vst
  attn        <<<dim3(36,16),   256, 0, stream>>>(q, slotA, vt, mk, mg, hsB, slotB, scl, 1); // kP dead -> comb
  gemm128     <<<dim3(36,10,1), 256, 0, stream>>>(slotB, WT + (size_t)3*1280*1280,
                                                  nullptr, nullptr, nullptr, (float*)d_out, bo, 1);
}

// Round 4
// 516.605 us; speedup vs baseline: 2.2454x; 1.0914x over previous
//
#include <hip/hip_runtime.h>

// Problem: B=2, S=2304, C=1280, NH=8, DH=160, MH=64, SR=48, BH=16
// R10: 564us (attn 2x169). V-LDS staging confirmed the V-gather theory.
//      BUT LDS 72.7KB -> 2 blocks/CU -> 576 blocks = 512 + 64-block tail at
//      6% occupancy; Occupancy 14.1% => tail ~= half the attn wall.
// R11: single-K + single-V rotated pipeline (LDS 51.7KB -> 3 blocks/CU, all
//      576 blocks resident, tail eliminated):
//        QK^T(kc) | barA (Ks consumed, V(kc) drained) | issue K(kc+1)
//        softmax+Ps+PV(kc) (covers K DMA) | barB | issue V(kc+1) (covered by
//        next QK^T + 3-block overlap).
//      Ps stride 72->76 u16 (quads hit distinct banks on writes).

typedef unsigned short u16;
typedef unsigned int   u32;
typedef unsigned char  u8;
typedef __attribute__((ext_vector_type(8))) short bf16x8;   // 8 bf16 = 4 VGPRs
typedef __attribute__((ext_vector_type(4))) float f32x4;

#define MFMA16(a,b,c) __builtin_amdgcn_mfma_f32_16x16x32_bf16((a),(b),(c),0,0,0)
#define INVS 0.07905694150420949f                 // 1/sqrt(160)
#define KPAD 168                                  // K row stride (u16): 84 dw -> b128 reads at bank floor
#define PSTR 76                                   // Ps row stride (u16): 38 dw -> write quads on distinct banks

typedef const __attribute__((address_space(1))) void gvoid;
typedef __attribute__((address_space(3))) void lvoid;
#define GLD16(gp, lp) __builtin_amdgcn_global_load_lds((gvoid*)(gp), (lvoid*)(lp), 16, 0, 0)

__device__ __forceinline__ u16 f2b(float f) {            // fp32 -> bf16 RNE
  u32 u = __float_as_uint(f);
  return (u16)((u + 0x7fffu + ((u >> 16) & 1u)) >> 16);
}
__device__ __forceinline__ float b2f(u16 v) { return __uint_as_float(((u32)v) << 16); }

// DPP reduction over a 16-lane row (exactly our l16 domain = one DPP row):
// quad_perm(1,0,3,2)=0xB1, quad_perm(2,3,0,1)=0x4E, row_half_mirror=0x141, row_mirror=0x140
#define DPPF(x, ctrl) __int_as_float(__builtin_amdgcn_update_dpp(0, __float_as_int(x), (ctrl), 0xf, 0xf, true))
__device__ __forceinline__ float row_max16(float x) {
  x = fmaxf(x, DPPF(x, 0xB1));
  x = fmaxf(x, DPPF(x, 0x4E));
  x = fmaxf(x, DPPF(x, 0x141));
  x = fmaxf(x, DPPF(x, 0x140));
  return x;
}
__device__ __forceinline__ float row_sum16(float x) {
  x += DPPF(x, 0xB1);
  x += DPPF(x, 0x4E);
  x += DPPF(x, 0x141);
  x += DPPF(x, 0x140);
  return x;
}

// ---------------- mask-mode detector: 0=i32, 1=u8, 2=bf16, 3=f32 ----------------
__global__ __launch_bounds__(256) void maskdet(const u32* __restrict__ mid, u32* mode)
{
  __shared__ int a0, a1, a2, a3;
  int tid = threadIdx.x;
  if (tid == 0) { a0 = 1; a1 = 1; a2 = 1; a3 = 0; }
  __syncthreads();
  #pragma unroll
  for (int j = 0; j < 4; j++) {
    u32 w = mid[tid*4 + j];                      // first 4 KiB, in-bounds for all dtypes
    if (w > 1u)                      atomicAnd(&a0, 0);  // not i32 bools
    if (w & 0xFEFEFEFEu)             atomicAnd(&a1, 0);  // not u8 bools
    if (w != 0u && w != 0x3F800000u) atomicAnd(&a2, 0);  // not f32 {0,1}
    if ((w & 0xFFFFu) == 0x3F80u)    atomicOr(&a3, 1);   // bf16 1.0 in low half
  }
  __syncthreads();
  if (tid == 0) mode[0] = a0 ? 0u : (a1 ? 1u : (a3 ? 2u : (a2 ? 3u : 0u)));
}

// ---------------- nearest-downsample masks 64x64 -> 48x48 flattened to S ----------------
__global__ void maskprep(const void* mid, const float* __restrict__ mig_in,
                         float* __restrict__ mk, float* __restrict__ mg, const u32* mode)
{
  int j = blockIdx.x*256 + threadIdx.x;
  if (j >= 2*2304) return;
  u32 md = mode[0];
  int b = j / 2304, s = j % 2304;
  int i = s / 48, jj = s % 48;
  int ih = (i*4)/3, iw = (jj*4)/3;        // arange(48)*64//48
  int src = b*4096 + ih*64 + iw;
  bool on;
  if      (md == 0) on = ((const int*)mid)[src] != 0;
  else if (md == 1) on = ((const u8*)mid)[src]  != 0;
  else if (md == 2) on = ((const u16*)mid)[src] != 0;
  else              on = ((const float*)mid)[src] != 0.0f;
  mk[j] = on ? 1.0f : 0.0f;
  mg[j] = mig_in[src];                     // mask_ig is fp32
}

// ---------------- transpose weights: fp32 W[k][n] -> bf16 WT[n][k], 4 matrices --------------
__global__ __launch_bounds__(256) void transpose_w(
    const float* __restrict__ W0, const float* __restrict__ W1,
    const float* __restrict__ W2, const float* __restrict__ W3, u16* __restrict__ WT)
{
  __shared__ u16 t[32][33];
  int z = blockIdx.z;
  const float* s = (z==0)?W0:(z==1)?W1:(z==2)?W2:W3;
  u16* d = WT + (size_t)z*1280*1280;
  int tx = threadIdx.x & 31, ty = (threadIdx.x >> 5) * 4;
  int x = blockIdx.x*32 + tx;          // src col (n)
  int y = blockIdx.y*32 + ty;          // src row (k)
  #pragma unroll
  for (int i=0;i<4;i++) t[ty+i][tx] = f2b(s[(size_t)(y+i)*1280 + x]);
  __syncthreads();
  int x2 = blockIdx.y*32 + tx, y2 = blockIdx.x*32 + ty;
  #pragma unroll
  for (int i=0;i<4;i++) d[(size_t)(y2+i)*1280 + x2] = t[tx][ty+i];   // WT[n][k] = W[k][n]
}

// ---------------- convert fp32 -> bf16 (unpadded) ----------------
__global__ __launch_bounds__(256) void conv(const float* __restrict__ src, u16* __restrict__ dst, int n)
{
  for (int i = blockIdx.x*256 + threadIdx.x; i < n; i += gridDim.x*256)
    dst[i] = f2b(src[i]);
}

// ---------------- convert store_ks fp32 [bh][s][160] -> padded bf16 [bh][s][168] ------------
__global__ __launch_bounds__(256) void convK(const float* __restrict__ src, u16* __restrict__ dst)
{
  const int n = 16*2304*KPAD;
  for (int i = blockIdx.x*256 + threadIdx.x; i < n; i += gridDim.x*256) {
    int row = i / KPAD, col = i % KPAD;
    dst[i] = (col < 160) ? f2b(src[(size_t)row*160 + col]) : (u16)0;
  }
}

// ---------------- transpose store_vs fp32 [16][2304][160] -> bf16 vst[16][160][2304] ---------
__global__ __launch_bounds__(256) void transpose_vs(const float* __restrict__ src, u16* __restrict__ dst)
{
  __shared__ u16 t[32][33];
  int z = blockIdx.z;
  u16* d = dst + (size_t)z*160*2304;
  int tx = threadIdx.x & 31, ty = (threadIdx.x >> 5) * 4;
  int r0 = blockIdx.x*32, c0 = blockIdx.y*32;
  #pragma unroll
  for (int i=0;i<4;i++)
    t[ty+i][tx] = f2b(src[((size_t)z*2304 + r0+ty+i)*160 + c0+tx]);
  __syncthreads();
  #pragma unroll
  for (int i=0;i<4;i++) d[(size_t)(c0+ty+i)*2304 + r0+tx] = t[tx][ty+i]; // d[c][r] = s[r][c]
}

// ---------------- GEMM: 128x128 tile, BK=32, 4 waves (2x2), 16x16x32 MFMA ----------------
// kind 0: A=hidB, BT=WT[z]; z=0->q*INVS [bh][s][160], z=1->k PADDED [bh][s][168], z=2->v^T [bh][d][s]
// kind 1: A=comb, BT=WoT;   out = A@Wo + bias -> fp32 d_out
__global__ __launch_bounds__(256, 2) void gemm128(
    const u16* __restrict__ A, const u16* __restrict__ BT,
    u16* __restrict__ dq, u16* __restrict__ dk, u16* __restrict__ dvt,
    float* __restrict__ dout, const float* __restrict__ bias, int kind)
{
  __shared__ __align__(16) u16 As[128*40];   // pad 32->40: 80B stride breaks conflicts
  __shared__ __align__(16) u16 Bs[128*40];
  int tid = threadIdx.x;
  int m0 = blockIdx.x*128, n0 = blockIdx.y*128;
  int z = blockIdx.z;
  const u16* Bt = BT + (size_t)z*1280*1280;
  int w = tid>>6, lane = tid&63, quad = lane>>4, l16 = lane&15;
  int wm = w&1, wn = w>>1;
  int arow = tid>>1, acg = (tid&1)*16;
  f32x4 zero = {0.f,0.f,0.f,0.f};
  f32x4 acc[4][4];
  #pragma unroll
  for (int a=0;a<4;a++) { acc[a][0]=zero; acc[a][1]=zero; acc[a][2]=zero; acc[a][3]=zero; }
  const u16* ga = A  + (size_t)(m0+arow)*1280 + acg;
  const u16* gb = Bt + (size_t)(n0+arow)*1280 + acg;
  for (int k0 = 0; k0 < 1280; k0 += 32) {
    uint4 a0 = *(const uint4*)(ga + k0);
    uint4 a1 = *(const uint4*)(ga + k0 + 8);
    uint4 b0 = *(const uint4*)(gb + k0);
    uint4 b1 = *(const uint4*)(gb + k0 + 8);
    __syncthreads();
    *(uint4*)&As[arow*40 + acg]     = a0;
    *(uint4*)&As[arow*40 + acg + 8] = a1;
    *(uint4*)&Bs[arow*40 + acg]     = b0;
    *(uint4*)&Bs[arow*40 + acg + 8] = b1;
    __syncthreads();
    bf16x8 af[4], bfr[4];
    #pragma unroll
    for (int mt=0; mt<4; mt++) af[mt]  = *(const bf16x8*)&As[(wm*64+mt*16+l16)*40 + quad*8];
    #pragma unroll
    for (int nt=0; nt<4; nt++) bfr[nt] = *(const bf16x8*)&Bs[(wn*64+nt*16+l16)*40 + quad*8];
    #pragma unroll
    for (int mt=0; mt<4; mt++)
      #pragma unroll
      for (int nt=0; nt<4; nt++)
        acc[mt][nt] = MFMA16(af[mt], bfr[nt], acc[mt][nt]);
  }
  #pragma unroll
  for (int mt=0; mt<4; mt++) {
    int r0g = m0 + wm*64 + mt*16 + quad*4;          // 4 consecutive rows (reg 0..3)
    #pragma unroll
    for (int nt=0; nt<4; nt++) {
      int col = n0 + wn*64 + nt*16 + l16;
      if (kind == 1) {
        float bi = bias[col];
        #pragma unroll
        for (int r=0;r<4;r++) dout[(size_t)(r0g+r)*1280 + col] = acc[mt][nt][r] + bi;
      } else {
        int h = col/160, d = col%160;
        if (z == 2) {                               // v -> [bh][d][s], s consecutive
          int b = r0g/2304, s0 = r0g%2304;
          size_t base = ((size_t)((b*8+h)*160 + d))*2304 + s0;
          ushort4 pk;
          pk.x = f2b(acc[mt][nt][0]); pk.y = f2b(acc[mt][nt][1]);
          pk.z = f2b(acc[mt][nt][2]); pk.w = f2b(acc[mt][nt][3]);
          *(ushort4*)&dvt[base] = pk;
        } else {
          #pragma unroll
          for (int r=0;r<4;r++) {
            int rg = r0g + r;
            int b = rg/2304, s = rg%2304;
            if (z == 0) dq[((size_t)(b*8+h)*2304 + s)*160  + d] = f2b(acc[mt][nt][r] * INVS);
            else        dk[((size_t)(b*8+h)*2304 + s)*KPAD + d] = f2b(acc[mt][nt][r]);
          }
        }
      }
    }
  }
}

// ---------------- Attention (flash-style, online softmax). ----------------
// ip=0: self -> hs (bf16). ip=1: keys=sksP, V=vst, per-key mask, combine -> comb bf16.
// SINGLE-buffered K and V, rotated pipeline (see header). LDS 51.7KB -> 3 blocks/CU,
// all 576 blocks resident -> no dispatch tail. K: lane-linear DMA of padded rows.
// V: per-lane-source DMA with XOR granule swizzle (slot=g^(d&7)) -> bank-floor b128.
__global__ __launch_bounds__(256, 3) void attn(
    const u16* __restrict__ qg,   // [16][2304][160], pre-scaled by INVS
    const u16* __restrict__ kg,   // PADDED [16][2304][168]
    const u16* __restrict__ vtg,  // [16][160][2304]
    const float* __restrict__ maskkey, const float* __restrict__ mig,
    u16* __restrict__ hs, u16* __restrict__ comb,
    const void* scaleptr, int ip)
{
  __shared__ __align__(16) u16 Ks[64*KPAD];     // 21504 B single buffer
  __shared__ __align__(16) u16 Vs[160*64];      // 20480 B, XOR-swizzled granules
  __shared__ __align__(16) u16 Ps[4*16*PSTR];   // 9728 B per-wave P relayout
  // XCD-aware remap: linear dispatch id round-robins XCDs (id%8). Give XCD c
  // bh {2c, 2c+1} so its working set (K 774KB + V 737KB per bh) fits 4MB L2.
  int id = blockIdx.y*36 + blockIdx.x;
  int xc = id & 7, kq = id >> 3;                 // kq in 0..71
  int bh = 2*xc + (kq >= 36 ? 1 : 0);
  int qt = (kq >= 36) ? kq - 36 : kq;
  int tid = threadIdx.x, w = tid>>6, lane = tid&63, quad = lane>>4, l16 = lane&15;
  int q0 = qt*64 + w*16;                         // wave's 16 queries

  const char* kgbytes = (const char*)kg;
  const char* ktile0 = kgbytes + ((size_t)bh*2304)*(KPAD*2);
  const char* vbytes = (const char*)vtg + ((size_t)bh*160)*2304*2;  // V^T slice base

  // V DMA lane geometry: instr j covers d-rows [j*8, j*8+8), 8 lanes per row.
  // Lane l fetches global granule ((l&7)^(l>>3)) of row j*8+(l>>3); LDS image
  // then has granule g of row d at byte d*128 + (g^(d&7))*16.
  int vrowl = lane>>3;                          // local d row 0..7
  int vgsw  = ((lane&7) ^ vrowl) << 4;          // swizzled source byte offset

  // ---- prologue: issue K(0) + V(0) DMA (both drained by the pre-loop barrier) ----
  {
    char* dst = (char*)Ks;
    int off = w*1024 + lane*16;
    #pragma unroll
    for (int j=0;j<5;j++) GLD16(ktile0 + j*4096 + off, dst + j*4096 + w*1024);
    if (w == 0) GLD16(ktile0 + 20480 + lane*16, dst + 20480);  // 21504-20480 tail
    #pragma unroll
    for (int j5=0;j5<5;j5++) {
      int j = w*5 + j5;
      GLD16(vbytes + (size_t)(j*8 + vrowl)*4608 + vgsw, (char*)Vs + j*1024);
    }
  }

  bf16x8 aq[5];                                // Q frags: A[m=l16][k=quad*8+j], 5 ksteps
  {
    const u16* qrow = qg + ((size_t)bh*2304 + q0 + l16)*160 + quad*8;
    #pragma unroll
    for (int ks=0; ks<5; ks++) aq[ks] = *(const bf16x8*)(qrow + ks*32);
  }
  f32x4 zero = {0.f,0.f,0.f,0.f};
  f32x4 o[10];
  #pragma unroll
  for (int i=0;i<10;i++) o[i] = zero;
  float mrun[4] = {-1e30f,-1e30f,-1e30f,-1e30f};
  float lrun[4] = {0.f,0.f,0.f,0.f};

  float mcur[4] = {1.f,1.f,1.f,1.f};
  if (ip) {
    #pragma unroll
    for (int nt=0;nt<4;nt++) mcur[nt] = maskkey[(bh & 1)*2304 + nt*16 + l16];
  }

  __syncthreads();                             // drains K(0)+V(0)+Q loads

  for (int kc = 0; kc < 36; kc++) {
    // ---- prefetch next iteration's mask values (off the score critical path) ----
    float mnxt[4] = {1.f,1.f,1.f,1.f};
    if (ip && kc < 35) {
      #pragma unroll
      for (int nt=0;nt<4;nt++) mnxt[nt] = maskkey[(bh & 1)*2304 + (kc+1)*64 + nt*16 + l16];
    }

    // ---- scores S[16 q][64 keys] = Q K^T (Q pre-scaled), K from LDS ----
    f32x4 sc[4];
    bool keep[4];
    #pragma unroll
    for (int nt=0; nt<4; nt++) {
      f32x4 s = zero;
      #pragma unroll
      for (int ks=0; ks<5; ks++) {
        bf16x8 bk = *(const bf16x8*)&Ks[(nt*16+l16)*KPAD + ks*32 + quad*8];
        s = MFMA16(aq[ks], bk, s);
      }
      keep[nt] = true;
      if (ip && mcur[nt] == 0.0f) {
        keep[nt] = false;
        #pragma unroll
        for (int r=0;r<4;r++) s[r] = -1e30f;
      }
      sc[nt] = s;
    }

    __syncthreads();                           // barA: Ks consumed by all waves

    // ---- issue K(kc+1) DMA into the (now free) single K buffer; drains at barB ----
    if (kc < 35) {
      const char* tile = ktile0 + (size_t)(kc+1)*64*(KPAD*2);
      char* dst = (char*)Ks;
      int off = w*1024 + lane*16;
      #pragma unroll
      for (int j=0;j<5;j++) GLD16(tile + j*4096 + off, dst + j*4096 + w*1024);
      if (w == 0) GLD16(tile + 20480 + lane*16, dst + 20480);
    }

    // ---- online softmax per query row (row = quad*4+r), DPP row reductions ----
    float p[4][4];
    #pragma unroll
    for (int r=0;r<4;r++) {
      float mrow = fmaxf(fmaxf(sc[0][r], sc[1][r]), fmaxf(sc[2][r], sc[3][r]));
      mrow = row_max16(mrow);
      float nm = fmaxf(mrun[r], mrow);
      float alpha = __expf(fminf(mrun[r] - nm, 0.f));
      mrun[r] = nm;
      float rs = 0.f;
      #pragma unroll
      for (int nt=0;nt<4;nt++) {
        float e = keep[nt] ? __expf(sc[nt][r] - nm) : 0.f;
        p[nt][r] = e; rs += e;
      }
      rs = row_sum16(rs);
      lrun[r] = lrun[r]*alpha + rs;
      #pragma unroll
      for (int nt2=0; nt2<10; nt2++) o[nt2][r] *= alpha;
    }

    // ---- P: C-layout -> A-layout via per-wave LDS (same-wave dep, compiler waits) ----
    #pragma unroll
    for (int nt=0;nt<4;nt++)
      #pragma unroll
      for (int r=0;r<4;r++)
        Ps[(w*16 + quad*4 + r)*PSTR + nt*16 + l16] = f2b(p[nt][r]);

    // ---- O += P V, V B-frags from LDS (XOR-swizzled, bank-floor b128 reads) ----
    #pragma unroll
    for (int kb=0; kb<2; kb++) {
      bf16x8 ap = *(const bf16x8*)&Ps[(w*16 + l16)*PSTR + kb*32 + quad*8];
      #pragma unroll
      for (int nt=0; nt<10; nt++) {
        int d = nt*16 + l16;
        bf16x8 bv = *(const bf16x8*)((const char*)Vs + d*128 + (((kb*4 + quad) ^ (l16 & 7)) << 4));
        o[nt] = MFMA16(ap, bv, o[nt]);
      }
    }

    if (ip) {
      #pragma unroll
      for (int nt=0;nt<4;nt++) mcur[nt] = mnxt[nt];
    }

    __syncthreads();                           // barB: K(kc+1) drained; Vs consumed by all

    // ---- issue V(kc+1) DMA (drains at next iter's barA, covered by QK^T +
    //      cross-block overlap at 3 blocks/CU) ----
    if (kc < 35) {
      const char* vsrc = vbytes + (size_t)(kc+1)*128;   // key-col offset (kc+1)*64 keys *2B
      #pragma unroll
      for (int j5=0;j5<5;j5++) {
        int j = w*5 + j5;
        GLD16(vsrc + (size_t)(j*8 + vrowl)*4608 + vgsw, (char*)Vs + j*1024);
      }
    }
  }

  // ---- epilogue ----
  int b = bh>>3, h = bh&7;
  float scl = 0.f;
  if (ip) {                                   // scalar dtype self-detect (0.5 decodes both ways)
    u16 v0 = ((const u16*)scaleptr)[0];
    int e = (v0 >> 7) & 0xFF;
    scl = (v0 != 0 && e >= 100 && e <= 133) ? b2f(v0) : ((const float*)scaleptr)[0];
  }
  #pragma unroll
  for (int r=0;r<4;r++) {
    int s = q0 + quad*4 + r;
    float linv = (lrun[r] > 0.f) ? 1.0f/lrun[r] : 0.f;
    size_t base = ((size_t)b*2304 + s)*1280 + h*160;
    if (!ip) {
      #pragma unroll
      for (int nt=0;nt<10;nt++) hs[base + nt*16 + l16] = f2b(o[nt][r]*linv);
    } else {
      float f = mig[b*2304 + s]*scl*linv;    // mig uses TRUE b
      #pragma unroll
      for (int nt=0;nt<10;nt++)
        comb[base + nt*16 + l16] = f2b(b2f(hs[base + nt*16 + l16]) + o[nt][r]*f);
    }
  }
}

// ---------------- launch ----------------
extern "C" void kernel_launch(void* const* d_in, const int* in_sizes, int n_in,
                              void* d_out, int out_size, void* d_ws, size_t ws_size,
                              hipStream_t stream)
{
  const float* hid = (const float*)d_in[0];
  const float* Wq  = (const float*)d_in[1];
  const float* Wk  = (const float*)d_in[2];
  const float* Wv  = (const float*)d_in[3];
  const float* Wo  = (const float*)d_in[4];
  const float* bo  = (const float*)d_in[5];
  const float* sks = (const float*)d_in[6];
  const float* svs = (const float*)d_in[7];
  const void*  mid = d_in[8];
  const float* mig = (const float*)d_in[9];
  const void*  scl = d_in[10];

  char* ws = (char*)d_ws;                    // 69.9 MiB total (aliased, stream-ordered)
  float* mk   = (float*)(ws);                // [2][2304]              18432 B
  float* mg   = (float*)(ws + 18432);        // [2][2304]              18432 B
  u32*  mode  = (u32*)(ws + 36864);          // 256 B
  u16*  WT    = (u16*)(ws + 40960);          // 4 x 1280x1280 bf16  13107200 B
  u16*  slotA = (u16*)(ws + 13148160);       // hidB unpadded; later sksP padded  12386304
  u16*  q     = (u16*)(ws + 25534464);       // [16][2304][160] (pre-scaled)      11796480
  u16*  slotB = (u16*)(ws + 37330944);       // kP padded; later comb             12386304
  u16*  vt    = (u16*)(ws + 49717248);       // v^T; later vst                    11796480
  u16*  hsB   = (u16*)(ws + 61513728);       // self-attn out bf16                11796480

  maskdet     <<<dim3(1),       256, 0, stream>>>((const u32*)mid, mode);
  maskprep    <<<dim3(18),      256, 0, stream>>>(mid, mig, mk, mg, mode);
  transpose_w <<<dim3(40,40,4), 256, 0, stream>>>(Wq, Wk, Wv, Wo, WT);
  conv        <<<dim3(2880),    256, 0, stream>>>(hid, slotA, 5898240);            // hidB
  gemm128     <<<dim3(36,10,3), 256, 0, stream>>>(slotA, WT, q, slotB, vt, nullptr, nullptr, 0);
  convK       <<<dim3(6048),    256, 0, stream>>>(sks, slotA);                     // hidB dead -> sksP
  attn        <<<dim3(36,16),   256, 0, stream>>>(q, slotB, vt, nullptr, nullptr, hsB, nullptr, scl, 0);
  transpose_vs<<<dim3(72,5,16), 256, 0, stream>>>(svs, vt);                        // vt dead -> vst
  attn        <<<dim3(36,16),   256, 0, stream>>>(q, slotA, vt, mk, mg, hsB, slotB, scl, 1); // kP dead -> comb
  gemm128     <<<dim3(36,10,1), 256, 0, stream>>>(slotB, WT + (size_t)3*1280*1280,
                                                  nullptr, nullptr, nullptr, (float*)d_out, bo, 1);
}